// Round 1
// baseline (510.434 us; speedup 1.0000x reference)
//
#include <hip/hip_runtime.h>
#include <stdint.h>

#define EPS 1e-8f
#define CAND_CAP 65536u
#define SEL_THREADS 1024
#define SEL_PER 64          // SEL_THREADS*SEL_PER == CAND_CAP
#define MAX_SEL 256
#define K_MIN 256u
#define FINF __uint_as_float(0x7f800000u)

// ---------------- content: e_i = exp(cos(mem_i, key)*beta), Z = sum e_i ----------
// wave64: 16 lanes per row (4 rows per wave per iter), fully coalesced float4 loads.
__global__ void content_kernel(const float* __restrict__ mem,
                               const float* __restrict__ key,
                               const float* __restrict__ beta_p,
                               float* __restrict__ e_out,
                               float* __restrict__ Zp, int n) {
    __shared__ float skey[64];
    __shared__ float swsum[8];
    int tid = threadIdx.x;
    if (tid < 64) skey[tid] = key[tid];
    __syncthreads();
    float kn = 0.f;
    #pragma unroll
    for (int i = 0; i < 64; ++i) { float v = skey[i]; kn = fmaf(v, v, kn); }
    float scale_k = beta_p[0] / fmaxf(sqrtf(kn), EPS);

    int lane = tid & 63;
    int sub  = lane & 15;   // column group (16 float4 = 64 cols)
    int rsub = lane >> 4;   // row within the wave's 4-row group
    float4 k4 = ((const float4*)skey)[sub];

    long long wave_id     = (long long)((blockIdx.x * blockDim.x + tid) >> 6);
    long long waves_total = (long long)((gridDim.x * blockDim.x) >> 6);
    float zloc = 0.f;
    for (long long row0 = wave_id * 4; row0 < n; row0 += waves_total * 4) {
        long long row = row0 + rsub;
        float4 v = ((const float4*)mem)[row * 16 + sub];
        float d = v.x*k4.x + v.y*k4.y + v.z*k4.z + v.w*k4.w;
        float s = v.x*v.x + v.y*v.y + v.z*v.z + v.w*v.w;
        #pragma unroll
        for (int off = 8; off >= 1; off >>= 1) {   // reduce within 16-lane row group
            d += __shfl_xor(d, off, 64);
            s += __shfl_xor(s, off, 64);
        }
        if (sub == 0) {
            float logit = d / fmaxf(sqrtf(s), EPS) * scale_k;   // |logit| <= ~2, no max-sub needed
            float e = __expf(logit);
            e_out[row] = e;
            zloc += e;
        }
    }
    #pragma unroll
    for (int off = 32; off >= 1; off >>= 1) zloc += __shfl_xor(zloc, off, 64);
    if (lane == 0) swsum[tid >> 6] = zloc;
    __syncthreads();
    if (tid == 0) {
        float z = 0.f;
        int nw = blockDim.x >> 6;
        for (int i = 0; i < nw; ++i) z += swsum[i];
        atomicAdd(Zp, z);
    }
}

// ---------------- usage + exponent histogram ----------------
__global__ void usage_kernel(const float* __restrict__ rw,
                             const float* __restrict__ fg,
                             const float* __restrict__ pu,
                             const float* __restrict__ pw,
                             float* __restrict__ us_out,
                             unsigned* __restrict__ hist, int n) {
    __shared__ unsigned lhist[256];
    int tid = threadIdx.x;            // blockDim == 256
    lhist[tid] = 0;
    __syncthreads();
    float f0 = fg[0], f1 = fg[1], f2 = fg[2], f3 = fg[3];
    float f4 = fg[4], f5 = fg[5], f6 = fg[6], f7 = fg[7];
    unsigned big = 0;
    int stride = gridDim.x * blockDim.x;
    for (int i = blockIdx.x * blockDim.x + tid; i < n; i += stride) {
        float4 a = ((const float4*)rw)[i * 2];
        float4 b = ((const float4*)rw)[i * 2 + 1];
        float ret = (1.f - a.x*f0) * (1.f - a.y*f1) * (1.f - a.z*f2) * (1.f - a.w*f3)
                  * (1.f - b.x*f4) * (1.f - b.y*f5) * (1.f - b.z*f6) * (1.f - b.w*f7);
        float u = pu[i], w = pw[i];
        float us = (u + w - u*w) * ret;
        us_out[i] = us;
        unsigned expo = (__float_as_uint(us) >> 23) & 0xffu;
        if (expo >= 120u) big++;                  // aggregate common big values (>=2^-7)
        else atomicAdd(&lhist[expo], 1u);         // rare small values
    }
    if (big) atomicAdd(&lhist[120], big);
    __syncthreads();
    if (lhist[tid]) atomicAdd(&hist[tid], lhist[tid]);
}

// ---------------- pick threshold T = upper edge of smallest exponent bin with cum >= K_MIN
__global__ void decide_kernel(const unsigned* __restrict__ hist, float* __restrict__ Tp) {
    unsigned cum = 0;
    int B = 255;
    for (int b = 0; b < 256; ++b) {
        unsigned c = hist[b];
        if (cum + c >= K_MIN) { B = (cum + c <= CAND_CAP) ? b : (b - 1); break; }
        cum += c;
    }
    float T;
    if (B < 0) T = 0.f;
    else if (B >= 254) T = __uint_as_float(0x7f800000u);
    else T = __uint_as_float(((unsigned)(B + 1)) << 23);   // 2^(B+1-127)
    *Tp = T;
}

// ---------------- collect candidates (usage < T) ----------------
__global__ void collect_kernel(const float* __restrict__ usage,
                               const float* __restrict__ Tp,
                               float* __restrict__ cand_val,
                               unsigned* __restrict__ cand_idx,
                               unsigned* __restrict__ counter, int n) {
    float T = *Tp;
    int stride = gridDim.x * blockDim.x;
    for (int i = blockIdx.x * blockDim.x + threadIdx.x; i < n; i += stride) {
        float u = usage[i];
        if (u < T) {
            unsigned p = atomicAdd(counter, 1u);
            if (p < CAND_CAP) { cand_val[p] = u; cand_idx[p] = i; }
        }
    }
}

// ---------------- single-block iterative argmin selection + exclusive cumprod --------
__global__ __launch_bounds__(SEL_THREADS)
void select_kernel(const float* __restrict__ cand_val,
                   const unsigned* __restrict__ cand_idx,
                   const unsigned* __restrict__ counter,
                   unsigned* __restrict__ sel_idx,
                   float* __restrict__ sel_alloc,
                   float* __restrict__ Sap,
                   unsigned* __restrict__ selcnt) {
    __shared__ float    wmin[SEL_THREADS / 64];
    __shared__ unsigned wpos[SEL_THREADS / 64];
    __shared__ float    bminS;
    __shared__ unsigned bposS;
    int tid = threadIdx.x;
    unsigned C = *counter; if (C > CAND_CAP) C = CAND_CAP;
    float v[SEL_PER];
    #pragma unroll
    for (int j = 0; j < SEL_PER; ++j) {
        unsigned p = (unsigned)(j * SEL_THREADS + tid);
        v[j] = (p < C) ? cand_val[p] : FINF;
    }
    float P = 1.f, Sa = 0.f;
    unsigned nsel = 0;
    for (int k = 0; k < MAX_SEL; ++k) {
        float lv = FINF;
        unsigned lpos = 0xffffffffu;
        #pragma unroll
        for (int j = 0; j < SEL_PER; ++j)
            if (v[j] < lv) { lv = v[j]; lpos = (unsigned)(j * SEL_THREADS + tid); }
        #pragma unroll
        for (int off = 32; off >= 1; off >>= 1) {
            float ov = __shfl_xor(lv, off, 64);
            unsigned op = __shfl_xor(lpos, off, 64);
            if (ov < lv) { lv = ov; lpos = op; }
        }
        if ((tid & 63) == 0) { wmin[tid >> 6] = lv; wpos[tid >> 6] = lpos; }
        __syncthreads();
        if (tid == 0) {
            float gm = wmin[0]; unsigned gp = wpos[0];
            #pragma unroll
            for (int i = 1; i < SEL_THREADS / 64; ++i)
                if (wmin[i] < gm) { gm = wmin[i]; gp = wpos[i]; }
            bminS = gm; bposS = gp;
        }
        __syncthreads();
        float gm = bminS; unsigned gp = bposS;
        if (!(gm < FINF) || P < 1e-38f) break;   // exhausted, or cumprod underflowed
        float a = (1.f - gm) * P;
        Sa += a; P *= gm; nsel++;
        if (tid == 0) { sel_alloc[k] = a; sel_idx[k] = cand_idx[gp]; }
        if ((gp & (unsigned)(SEL_THREADS - 1)) == (unsigned)tid) {
            unsigned jj = gp / SEL_THREADS;
            #pragma unroll
            for (int j = 0; j < SEL_PER; ++j)
                if ((unsigned)j == jj) v[j] = FINF;   // retire winner slot
        }
    }
    if (tid == 0) { *Sap = Sa; *selcnt = nsel; }
}

// ---------------- final elementwise: ww (content part) + new precedence ----------
__global__ void final_kernel(const float* __restrict__ e,
                             const float* __restrict__ prec,
                             const float* __restrict__ Zp,
                             const float* __restrict__ Sap,
                             const float* __restrict__ wg_p,
                             const float* __restrict__ ag_p,
                             float* __restrict__ out_ww,
                             float* __restrict__ out_prec, int n) {
    float Z = *Zp, Sa = *Sap, wg = *wg_p, ag = *ag_p;
    float cscale = wg * (1.f - ag) / Z;
    // sum(ww) = wg*(ag*sum(alloc) + (1-ag)*sum(softmax)); sum(softmax)==1 by construction
    float om = 1.f - wg * (ag * Sa + (1.f - ag));
    int stride = gridDim.x * blockDim.x;
    for (int i = blockIdx.x * blockDim.x + threadIdx.x; i < n; i += stride) {
        float wwc = cscale * e[i];
        out_ww[i] = wwc;
        out_prec[i] = om * prec[i] + wwc;
    }
}

// ---------------- scatter the (few) nonzero alloc contributions ----------------
__global__ void scatter_kernel(const unsigned* __restrict__ sel_idx,
                               const float* __restrict__ sel_alloc,
                               const unsigned* __restrict__ selcnt,
                               const float* __restrict__ wg_p,
                               const float* __restrict__ ag_p,
                               float* __restrict__ out_ww,
                               float* __restrict__ out_prec) {
    unsigned c = *selcnt;
    float coef = wg_p[0] * ag_p[0];
    unsigned t = threadIdx.x;
    if (t < c) {
        unsigned idx = sel_idx[t];
        float add = coef * sel_alloc[t];
        out_ww[idx] += add;
        out_prec[idx] += add;
    }
}

extern "C" void kernel_launch(void* const* d_in, const int* in_sizes, int n_in,
                              void* d_out, int out_size, void* d_ws, size_t ws_size,
                              hipStream_t stream) {
    const float* memory = (const float*)d_in[0];
    const float* wkey   = (const float*)d_in[1];
    const float* beta   = (const float*)d_in[2];
    const float* fgate  = (const float*)d_in[3];
    const float* rw     = (const float*)d_in[4];
    const float* pu     = (const float*)d_in[5];
    const float* pww    = (const float*)d_in[6];
    const float* agate  = (const float*)d_in[7];
    const float* wgate  = (const float*)d_in[8];
    const float* prec   = (const float*)d_in[9];
    int n = in_sizes[5];                       // 1048576 rows

    float* out_ww = (float*)d_out;
    float* out_us = out_ww + n;
    float* out_pr = out_ww + 2 * (size_t)n;

    char* ws = (char*)d_ws;
    float* e_buf = (float*)ws;                            // n floats
    char* ctrl = ws + (size_t)n * 4;
    float*    Zp       = (float*)(ctrl + 0);
    unsigned* counter  = (unsigned*)(ctrl + 4);
    float*    Tp       = (float*)(ctrl + 8);
    unsigned* selcnt   = (unsigned*)(ctrl + 12);
    float*    Sap      = (float*)(ctrl + 16);
    unsigned* hist     = (unsigned*)(ctrl + 32);          // 256 bins
    unsigned* sel_idx  = (unsigned*)(ctrl + 32 + 1024);   // MAX_SEL
    float*    sel_all  = (float*)(ctrl + 32 + 2048);      // MAX_SEL
    float*    cand_val = (float*)(ctrl + 4096);           // CAND_CAP
    unsigned* cand_idx = (unsigned*)(ctrl + 4096 + CAND_CAP * 4);

    hipMemsetAsync(ctrl, 0, 4096, stream);   // zero Z, counter, hist header

    content_kernel<<<4096, 256, 0, stream>>>(memory, wkey, beta, e_buf, Zp, n);
    usage_kernel<<<2048, 256, 0, stream>>>(rw, fgate, pu, pww, out_us, hist, n);
    decide_kernel<<<1, 1, 0, stream>>>(hist, Tp);
    collect_kernel<<<1024, 256, 0, stream>>>(out_us, Tp, cand_val, cand_idx, counter, n);
    select_kernel<<<1, SEL_THREADS, 0, stream>>>(cand_val, cand_idx, counter,
                                                 sel_idx, sel_all, Sap, selcnt);
    final_kernel<<<2048, 256, 0, stream>>>(e_buf, prec, Zp, Sap, wgate, agate,
                                           out_ww, out_pr, n);
    scatter_kernel<<<1, MAX_SEL, 0, stream>>>(sel_idx, sel_all, selcnt, wgate, agate,
                                              out_ww, out_pr);
}

// Round 2
// 488.385 us; speedup vs baseline: 1.0451x; 1.0451x over previous
//
#include <hip/hip_runtime.h>
#include <stdint.h>

#define EPS 1e-8f
#define CAND_CAP 65536u
#define SEL_THREADS 1024
#define SEL_PER 64          // SEL_THREADS*SEL_PER == CAND_CAP
#define MAX_SEL 256
#define K_MIN 256u
#define FINF __uint_as_float(0x7f800000u)

// ============ K1: content (e_i, Z) + usage (us_i, exponent histogram) ============
__global__ __launch_bounds__(256)
void k1_content_usage(const float* __restrict__ mem,
                      const float* __restrict__ key,
                      const float* __restrict__ beta_p,
                      const float* __restrict__ rw,
                      const float* __restrict__ fg,
                      const float* __restrict__ pu,
                      const float* __restrict__ pw,
                      float* __restrict__ e_out,
                      float* __restrict__ us_out,
                      float* __restrict__ Zp,
                      unsigned* __restrict__ hist, int n) {
    __shared__ float skey[64];
    __shared__ float swsum[4];
    __shared__ unsigned lhist[256];
    int tid = threadIdx.x;
    if (tid < 64) skey[tid] = key[tid];
    lhist[tid] = 0;
    __syncthreads();

    float kn = 0.f;
    #pragma unroll
    for (int i = 0; i < 64; ++i) { float v = skey[i]; kn = fmaf(v, v, kn); }
    float scale_k = beta_p[0] / fmaxf(sqrtf(kn), EPS);

    // ---- phase A: content. 16 lanes per row, 4 rows per wave per iter ----
    int lane = tid & 63;
    int sub  = lane & 15;
    int rsub = lane >> 4;
    float4 k4 = ((const float4*)skey)[sub];

    int wave_id     = (blockIdx.x * 256 + tid) >> 6;
    int waves_total = (gridDim.x * 256) >> 6;
    float zloc = 0.f;
    for (int row0 = wave_id * 4; row0 < n; row0 += waves_total * 4) {
        int row = row0 + rsub;
        float4 v = ((const float4*)mem)[row * 16 + sub];
        float d = v.x*k4.x + v.y*k4.y + v.z*k4.z + v.w*k4.w;
        float s = v.x*v.x + v.y*v.y + v.z*v.z + v.w*v.w;
        #pragma unroll
        for (int off = 8; off >= 1; off >>= 1) {
            d += __shfl_xor(d, off, 64);
            s += __shfl_xor(s, off, 64);
        }
        if (sub == 0) {
            float logit = d / fmaxf(sqrtf(s), EPS) * scale_k;  // |logit| <= ~2
            float e = __expf(logit);
            e_out[row] = e;
            zloc += e;
        }
    }
    #pragma unroll
    for (int off = 32; off >= 1; off >>= 1) zloc += __shfl_xor(zloc, off, 64);
    if (lane == 0) swsum[tid >> 6] = zloc;

    // ---- phase B: usage + histogram (independent of phase A) ----
    float f0 = fg[0], f1 = fg[1], f2 = fg[2], f3 = fg[3];
    float f4 = fg[4], f5 = fg[5], f6 = fg[6], f7 = fg[7];
    unsigned big = 0;
    int stride = gridDim.x * 256;
    for (int i = blockIdx.x * 256 + tid; i < n; i += stride) {
        float4 a = ((const float4*)rw)[i * 2];
        float4 b = ((const float4*)rw)[i * 2 + 1];
        float ret = (1.f - a.x*f0) * (1.f - a.y*f1) * (1.f - a.z*f2) * (1.f - a.w*f3)
                  * (1.f - b.x*f4) * (1.f - b.y*f5) * (1.f - b.z*f6) * (1.f - b.w*f7);
        float u = pu[i], w = pw[i];
        float us = (u + w - u*w) * ret;
        us_out[i] = us;
        unsigned expo = (__float_as_uint(us) >> 23) & 0xffu;
        if (expo >= 120u) big++;               // common case aggregated in-register
        else atomicAdd(&lhist[expo], 1u);      // rare small values
    }
    if (big) atomicAdd(&lhist[120], big);
    __syncthreads();
    if (tid == 0) {
        atomicAdd(Zp, swsum[0] + swsum[1] + swsum[2] + swsum[3]);
    }
    unsigned c = lhist[tid];
    if (c) atomicAdd(&hist[tid], c);
}

// ============ K2: final elementwise (ww, prec) + threshold decide + collect ============
// sum(alloc) telescopes to 1 - prod(all usage) == 1 exactly in fp32 (1M factors < 1),
// and sum(softmax) == 1, so om = 1 - wg: no dependency on the selection pass.
__global__ __launch_bounds__(256)
void k2_final_collect(const float* __restrict__ e,
                      const float* __restrict__ prec,
                      const float* __restrict__ usage,
                      const unsigned* __restrict__ hist,
                      const float* __restrict__ Zp,
                      const float* __restrict__ wg_p,
                      const float* __restrict__ ag_p,
                      float* __restrict__ out_ww,
                      float* __restrict__ out_prec,
                      float* __restrict__ cand_val,
                      unsigned* __restrict__ cand_idx,
                      unsigned* __restrict__ counter, int n4) {
    __shared__ unsigned shist[256];
    __shared__ float sT;
    int tid = threadIdx.x;
    shist[tid] = hist[tid];
    __syncthreads();
    if (tid == 0) {
        unsigned cum = 0; int B = 255;
        for (int b = 0; b < 256; ++b) {
            unsigned c = shist[b];
            if (cum + c >= K_MIN) { B = (cum + c <= CAND_CAP) ? b : (b - 1); break; }
            cum += c;
        }
        float T;
        if (B < 0) T = 0.f;
        else if (B >= 254) T = FINF;
        else T = __uint_as_float(((unsigned)(B + 1)) << 23);   // 2^(B+1-127)
        sT = T;
    }
    __syncthreads();
    float T = sT;
    float Z = *Zp, wg = *wg_p, ag = *ag_p;
    float cscale = wg * (1.f - ag) / Z;
    float om = 1.f - wg;
    int stride = gridDim.x * 256;
    for (int i = blockIdx.x * 256 + tid; i < n4; i += stride) {
        float4 ev = ((const float4*)e)[i];
        float4 pv = ((const float4*)prec)[i];
        float4 uv = ((const float4*)usage)[i];
        float4 ww, pr;
        ww.x = cscale * ev.x; ww.y = cscale * ev.y;
        ww.z = cscale * ev.z; ww.w = cscale * ev.w;
        pr.x = om * pv.x + ww.x; pr.y = om * pv.y + ww.y;
        pr.z = om * pv.z + ww.z; pr.w = om * pv.w + ww.w;
        ((float4*)out_ww)[i] = ww;
        ((float4*)out_prec)[i] = pr;
        int base = i * 4;
        if (uv.x < T) { unsigned p = atomicAdd(counter, 1u); if (p < CAND_CAP) { cand_val[p] = uv.x; cand_idx[p] = base; } }
        if (uv.y < T) { unsigned p = atomicAdd(counter, 1u); if (p < CAND_CAP) { cand_val[p] = uv.y; cand_idx[p] = base + 1; } }
        if (uv.z < T) { unsigned p = atomicAdd(counter, 1u); if (p < CAND_CAP) { cand_val[p] = uv.z; cand_idx[p] = base + 2; } }
        if (uv.w < T) { unsigned p = atomicAdd(counter, 1u); if (p < CAND_CAP) { cand_val[p] = uv.w; cand_idx[p] = base + 3; } }
    }
}

// ============ K3: single-block argmin selection + exclusive cumprod + scatter ============
__global__ __launch_bounds__(SEL_THREADS)
void k3_select_scatter(const float* __restrict__ cand_val,
                       const unsigned* __restrict__ cand_idx,
                       const unsigned* __restrict__ counter,
                       const float* __restrict__ wg_p,
                       const float* __restrict__ ag_p,
                       float* __restrict__ out_ww,
                       float* __restrict__ out_prec) {
    __shared__ float    wmin[SEL_THREADS / 64];
    __shared__ unsigned wpos[SEL_THREADS / 64];
    __shared__ float    bminS;
    __shared__ unsigned bposS;
    __shared__ float    s_alloc[MAX_SEL];
    __shared__ unsigned s_idx[MAX_SEL];
    int tid = threadIdx.x;
    unsigned C = *counter; if (C > CAND_CAP) C = CAND_CAP;
    float v[SEL_PER];
    #pragma unroll
    for (int j = 0; j < SEL_PER; ++j) {
        unsigned p = (unsigned)(j * SEL_THREADS + tid);
        v[j] = (p < C) ? cand_val[p] : FINF;
    }
    float P = 1.f;
    unsigned nsel = 0;
    for (int k = 0; k < MAX_SEL; ++k) {
        float lv = FINF;
        unsigned lpos = 0xffffffffu;
        #pragma unroll
        for (int j = 0; j < SEL_PER; ++j)
            if (v[j] < lv) { lv = v[j]; lpos = (unsigned)(j * SEL_THREADS + tid); }
        #pragma unroll
        for (int off = 32; off >= 1; off >>= 1) {
            float ov = __shfl_xor(lv, off, 64);
            unsigned op = __shfl_xor(lpos, off, 64);
            if (ov < lv) { lv = ov; lpos = op; }
        }
        if ((tid & 63) == 0) { wmin[tid >> 6] = lv; wpos[tid >> 6] = lpos; }
        __syncthreads();
        if (tid == 0) {
            float gm = wmin[0]; unsigned gp = wpos[0];
            #pragma unroll
            for (int i = 1; i < SEL_THREADS / 64; ++i)
                if (wmin[i] < gm) { gm = wmin[i]; gp = wpos[i]; }
            bminS = gm; bposS = gp;
        }
        __syncthreads();
        float gm = bminS; unsigned gp = bposS;
        if (!(gm < FINF) || P < 1e-38f) break;   // exhausted or cumprod underflowed
        if (tid == 0) { s_alloc[k] = (1.f - gm) * P; s_idx[k] = cand_idx[gp]; }
        P *= gm; nsel++;
        if ((gp & (unsigned)(SEL_THREADS - 1)) == (unsigned)tid) {
            unsigned jj = gp / SEL_THREADS;
            #pragma unroll
            for (int j = 0; j < SEL_PER; ++j)
                if ((unsigned)j == jj) v[j] = FINF;   // retire winner slot
        }
    }
    __syncthreads();
    // scatter: add gated alloc onto the already-written outputs
    float coef = wg_p[0] * ag_p[0];
    if ((unsigned)tid < nsel) {
        unsigned idx = s_idx[tid];
        float add = coef * s_alloc[tid];
        out_ww[idx]   += add;
        out_prec[idx] += add;
    }
}

extern "C" void kernel_launch(void* const* d_in, const int* in_sizes, int n_in,
                              void* d_out, int out_size, void* d_ws, size_t ws_size,
                              hipStream_t stream) {
    const float* memory = (const float*)d_in[0];
    const float* wkey   = (const float*)d_in[1];
    const float* beta   = (const float*)d_in[2];
    const float* fgate  = (const float*)d_in[3];
    const float* rw     = (const float*)d_in[4];
    const float* pu     = (const float*)d_in[5];
    const float* pww    = (const float*)d_in[6];
    const float* agate  = (const float*)d_in[7];
    const float* wgate  = (const float*)d_in[8];
    const float* prec   = (const float*)d_in[9];
    int n = in_sizes[5];                       // 1048576 rows

    float* out_ww = (float*)d_out;
    float* out_us = out_ww + n;
    float* out_pr = out_ww + 2 * (size_t)n;

    char* ws = (char*)d_ws;
    float* e_buf = (float*)ws;                            // n floats
    char* ctrl = ws + (size_t)n * 4;
    float*    Zp       = (float*)(ctrl + 0);
    unsigned* counter  = (unsigned*)(ctrl + 4);
    unsigned* hist     = (unsigned*)(ctrl + 32);          // 256 bins
    float*    cand_val = (float*)(ctrl + 4096);           // CAND_CAP
    unsigned* cand_idx = (unsigned*)(ctrl + 4096 + CAND_CAP * 4);

    hipMemsetAsync(ctrl, 0, 4096, stream);   // zero Z, counter, hist

    k1_content_usage<<<2048, 256, 0, stream>>>(memory, wkey, beta, rw, fgate, pu, pww,
                                               e_buf, out_us, Zp, hist, n);
    k2_final_collect<<<1024, 256, 0, stream>>>(e_buf, prec, out_us, hist, Zp, wgate, agate,
                                               out_ww, out_pr, cand_val, cand_idx, counter,
                                               n / 4);
    k3_select_scatter<<<1, SEL_THREADS, 0, stream>>>(cand_val, cand_idx, counter,
                                                     wgate, agate, out_ww, out_pr);
}

// Round 3
// 487.881 us; speedup vs baseline: 1.0462x; 1.0010x over previous
//
#include <hip/hip_runtime.h>
#include <stdint.h>

#define EPS 1e-8f
#define CAND_CAP 65536u
#define SEL_THREADS 1024
#define SEL_PER 64          // SEL_THREADS*SEL_PER == CAND_CAP
#define MAX_SEL 256
#define K_MIN 256u
#define FINF __uint_as_float(0x7f800000u)

#define K1_GRID 2048
#define K1_BLOCK 256
// rows per grid-iteration in phase A: (K1_GRID*K1_BLOCK/64) waves * 4 rows
#define ROWS_PER_ITER (K1_GRID * K1_BLOCK / 64 * 4)   // 32768

// ============ K1: content (e_i, Z) + usage (us_i, exponent histogram) ============
__global__ __launch_bounds__(K1_BLOCK)
void k1_content_usage(const float* __restrict__ mem,
                      const float* __restrict__ key,
                      const float* __restrict__ beta_p,
                      const float* __restrict__ rw,
                      const float* __restrict__ fg,
                      const float* __restrict__ pu,
                      const float* __restrict__ pw,
                      float* __restrict__ e_out,
                      float* __restrict__ us_out,
                      float* __restrict__ Zp,
                      unsigned* __restrict__ hist, int n) {
    __shared__ float skey[64];
    __shared__ float swsum[4];
    __shared__ unsigned lhist[256];
    int tid = threadIdx.x;
    if (tid < 64) skey[tid] = key[tid];
    lhist[tid] = 0;
    __syncthreads();

    float kn = 0.f;
    #pragma unroll
    for (int i = 0; i < 64; ++i) { float v = skey[i]; kn = fmaf(v, v, kn); }
    float scale_k = beta_p[0] / fmaxf(sqrtf(kn), EPS);

    // ---- phase A: content. 16 lanes per row, 4 rows per wave per iter ----
    int lane = tid & 63;
    int sub  = lane & 15;
    int rsub = lane >> 4;
    float4 k4 = ((const float4*)skey)[sub];

    int wave_id = (blockIdx.x * K1_BLOCK + tid) >> 6;
    float zloc = 0.f;

    if (n == ROWS_PER_ITER * 32) {          // fast path: compile-time trip count & stride
        int row = wave_id * 4 + rsub;
        const float4* mp = (const float4*)mem + (size_t)row * 16 + sub;
        #pragma unroll 4
        for (int it = 0; it < 32; ++it) {
            float4 v = mp[(size_t)it * (ROWS_PER_ITER * 16)];
            float d = v.x*k4.x + v.y*k4.y + v.z*k4.z + v.w*k4.w;
            float s = v.x*v.x + v.y*v.y + v.z*v.z + v.w*v.w;
            #pragma unroll
            for (int off = 8; off >= 1; off >>= 1) {
                d += __shfl_xor(d, off, 64);
                s += __shfl_xor(s, off, 64);
            }
            float e = __expf(d / fmaxf(sqrtf(s), EPS) * scale_k);  // |logit| <= ~2
            if (sub == 0) {
                e_out[row + it * ROWS_PER_ITER] = e;
                zloc += e;
            }
        }
    } else {                                 // generic fallback
        int waves_total = (gridDim.x * K1_BLOCK) >> 6;
        for (int row0 = wave_id * 4; row0 < n; row0 += waves_total * 4) {
            int row = row0 + rsub;
            float4 v = ((const float4*)mem)[(size_t)row * 16 + sub];
            float d = v.x*k4.x + v.y*k4.y + v.z*k4.z + v.w*k4.w;
            float s = v.x*v.x + v.y*v.y + v.z*v.z + v.w*v.w;
            #pragma unroll
            for (int off = 8; off >= 1; off >>= 1) {
                d += __shfl_xor(d, off, 64);
                s += __shfl_xor(s, off, 64);
            }
            float e = __expf(d / fmaxf(sqrtf(s), EPS) * scale_k);
            if (sub == 0) { e_out[row] = e; zloc += e; }
        }
    }
    #pragma unroll
    for (int off = 32; off >= 1; off >>= 1) zloc += __shfl_xor(zloc, off, 64);
    if (lane == 0) swsum[tid >> 6] = zloc;

    // ---- phase B: usage + histogram (independent of phase A) ----
    float f0 = fg[0], f1 = fg[1], f2 = fg[2], f3 = fg[3];
    float f4 = fg[4], f5 = fg[5], f6 = fg[6], f7 = fg[7];
    unsigned big = 0;
    int stride = gridDim.x * K1_BLOCK;
    for (int i = blockIdx.x * K1_BLOCK + tid; i < n; i += stride) {
        float4 a = ((const float4*)rw)[i * 2];
        float4 b = ((const float4*)rw)[i * 2 + 1];
        float ret = (1.f - a.x*f0) * (1.f - a.y*f1) * (1.f - a.z*f2) * (1.f - a.w*f3)
                  * (1.f - b.x*f4) * (1.f - b.y*f5) * (1.f - b.z*f6) * (1.f - b.w*f7);
        float u = pu[i], w = pw[i];
        float us = (u + w - u*w) * ret;
        us_out[i] = us;
        unsigned expo = (__float_as_uint(us) >> 23) & 0xffu;
        if (expo >= 120u) big++;               // common case aggregated in-register
        else atomicAdd(&lhist[expo], 1u);      // rare small values
    }
    if (big) atomicAdd(&lhist[120], big);
    __syncthreads();
    if (tid == 0) {
        atomicAdd(Zp, swsum[0] + swsum[1] + swsum[2] + swsum[3]);
    }
    unsigned c = lhist[tid];
    if (c) atomicAdd(&hist[tid], c);
}

// ============ K2: final elementwise (ww, prec) + threshold decide + collect ============
// sum(alloc) telescopes to 1 - prod(all usage) == 1 exactly in fp32 (1M factors < 1),
// and sum(softmax) == 1, so om = 1 - wg: no dependency on the selection pass.
__global__ __launch_bounds__(256)
void k2_final_collect(const float* __restrict__ e,
                      const float* __restrict__ prec,
                      const float* __restrict__ usage,
                      const unsigned* __restrict__ hist,
                      const float* __restrict__ Zp,
                      const float* __restrict__ wg_p,
                      const float* __restrict__ ag_p,
                      float* __restrict__ out_ww,
                      float* __restrict__ out_prec,
                      float* __restrict__ cand_val,
                      unsigned* __restrict__ cand_idx,
                      unsigned* __restrict__ counter, int n4) {
    __shared__ unsigned shist[256];
    __shared__ float sT;
    int tid = threadIdx.x;
    shist[tid] = hist[tid];
    __syncthreads();
    if (tid == 0) {
        unsigned cum = 0; int B = 255;
        for (int b = 0; b < 256; ++b) {
            unsigned c = shist[b];
            if (cum + c >= K_MIN) { B = (cum + c <= CAND_CAP) ? b : (b - 1); break; }
            cum += c;
        }
        float T;
        if (B < 0) T = 0.f;
        else if (B >= 254) T = FINF;
        else T = __uint_as_float(((unsigned)(B + 1)) << 23);   // 2^(B+1-127)
        sT = T;
    }
    __syncthreads();
    float T = sT;
    float Z = *Zp, wg = *wg_p, ag = *ag_p;
    float cscale = wg * (1.f - ag) / Z;
    float om = 1.f - wg;
    int stride = gridDim.x * 256;
    for (int i = blockIdx.x * 256 + tid; i < n4; i += stride) {
        float4 ev = ((const float4*)e)[i];
        float4 pv = ((const float4*)prec)[i];
        float4 uv = ((const float4*)usage)[i];
        float4 ww, pr;
        ww.x = cscale * ev.x; ww.y = cscale * ev.y;
        ww.z = cscale * ev.z; ww.w = cscale * ev.w;
        pr.x = om * pv.x + ww.x; pr.y = om * pv.y + ww.y;
        pr.z = om * pv.z + ww.z; pr.w = om * pv.w + ww.w;
        ((float4*)out_ww)[i] = ww;
        ((float4*)out_prec)[i] = pr;
        int base = i * 4;
        if (uv.x < T) { unsigned p = atomicAdd(counter, 1u); if (p < CAND_CAP) { cand_val[p] = uv.x; cand_idx[p] = base; } }
        if (uv.y < T) { unsigned p = atomicAdd(counter, 1u); if (p < CAND_CAP) { cand_val[p] = uv.y; cand_idx[p] = base + 1; } }
        if (uv.z < T) { unsigned p = atomicAdd(counter, 1u); if (p < CAND_CAP) { cand_val[p] = uv.z; cand_idx[p] = base + 2; } }
        if (uv.w < T) { unsigned p = atomicAdd(counter, 1u); if (p < CAND_CAP) { cand_val[p] = uv.w; cand_idx[p] = base + 3; } }
    }
}

// ============ K3: single-block argmin selection + exclusive cumprod + scatter ============
__global__ __launch_bounds__(SEL_THREADS)
void k3_select_scatter(const float* __restrict__ cand_val,
                       const unsigned* __restrict__ cand_idx,
                       const unsigned* __restrict__ counter,
                       const float* __restrict__ wg_p,
                       const float* __restrict__ ag_p,
                       float* __restrict__ out_ww,
                       float* __restrict__ out_prec) {
    __shared__ float    wmin[SEL_THREADS / 64];
    __shared__ unsigned wpos[SEL_THREADS / 64];
    __shared__ float    bminS;
    __shared__ unsigned bposS;
    __shared__ float    s_alloc[MAX_SEL];
    __shared__ unsigned s_idx[MAX_SEL];
    int tid = threadIdx.x;
    unsigned C = *counter; if (C > CAND_CAP) C = CAND_CAP;
    float v[SEL_PER];
    #pragma unroll
    for (int j = 0; j < SEL_PER; ++j) {
        unsigned p = (unsigned)(j * SEL_THREADS + tid);
        v[j] = (p < C) ? cand_val[p] : FINF;
    }
    float P = 1.f;
    unsigned nsel = 0;
    for (int k = 0; k < MAX_SEL; ++k) {
        float lv = FINF;
        unsigned lpos = 0xffffffffu;
        #pragma unroll
        for (int j = 0; j < SEL_PER; ++j)
            if (v[j] < lv) { lv = v[j]; lpos = (unsigned)(j * SEL_THREADS + tid); }
        #pragma unroll
        for (int off = 32; off >= 1; off >>= 1) {
            float ov = __shfl_xor(lv, off, 64);
            unsigned op = __shfl_xor(lpos, off, 64);
            if (ov < lv) { lv = ov; lpos = op; }
        }
        if ((tid & 63) == 0) { wmin[tid >> 6] = lv; wpos[tid >> 6] = lpos; }
        __syncthreads();
        if (tid == 0) {
            float gm = wmin[0]; unsigned gp = wpos[0];
            #pragma unroll
            for (int i = 1; i < SEL_THREADS / 64; ++i)
                if (wmin[i] < gm) { gm = wmin[i]; gp = wpos[i]; }
            bminS = gm; bposS = gp;
        }
        __syncthreads();
        float gm = bminS; unsigned gp = bposS;
        if (!(gm < FINF) || P < 1e-38f) break;   // exhausted or cumprod underflowed
        if (tid == 0) { s_alloc[k] = (1.f - gm) * P; s_idx[k] = cand_idx[gp]; }
        P *= gm; nsel++;
        if ((gp & (unsigned)(SEL_THREADS - 1)) == (unsigned)tid) {
            unsigned jj = gp / SEL_THREADS;
            #pragma unroll
            for (int j = 0; j < SEL_PER; ++j)
                if ((unsigned)j == jj) v[j] = FINF;   // retire winner slot
        }
    }
    __syncthreads();
    // scatter: add gated alloc onto the already-written outputs
    float coef = wg_p[0] * ag_p[0];
    if ((unsigned)tid < nsel) {
        unsigned idx = s_idx[tid];
        float add = coef * s_alloc[tid];
        out_ww[idx]   += add;
        out_prec[idx] += add;
    }
}

extern "C" void kernel_launch(void* const* d_in, const int* in_sizes, int n_in,
                              void* d_out, int out_size, void* d_ws, size_t ws_size,
                              hipStream_t stream) {
    const float* memory = (const float*)d_in[0];
    const float* wkey   = (const float*)d_in[1];
    const float* beta   = (const float*)d_in[2];
    const float* fgate  = (const float*)d_in[3];
    const float* rw     = (const float*)d_in[4];
    const float* pu     = (const float*)d_in[5];
    const float* pww    = (const float*)d_in[6];
    const float* agate  = (const float*)d_in[7];
    const float* wgate  = (const float*)d_in[8];
    const float* prec   = (const float*)d_in[9];
    int n = in_sizes[5];                       // 1048576 rows

    float* out_ww = (float*)d_out;
    float* out_us = out_ww + n;
    float* out_pr = out_ww + 2 * (size_t)n;

    char* ws = (char*)d_ws;
    float* e_buf = (float*)ws;                            // n floats
    char* ctrl = ws + (size_t)n * 4;
    float*    Zp       = (float*)(ctrl + 0);
    unsigned* counter  = (unsigned*)(ctrl + 4);
    unsigned* hist     = (unsigned*)(ctrl + 32);          // 256 bins
    float*    cand_val = (float*)(ctrl + 4096);           // CAND_CAP
    unsigned* cand_idx = (unsigned*)(ctrl + 4096 + CAND_CAP * 4);

    hipMemsetAsync(ctrl, 0, 4096, stream);   // zero Z, counter, hist

    k1_content_usage<<<K1_GRID, K1_BLOCK, 0, stream>>>(memory, wkey, beta, rw, fgate,
                                                       pu, pww, e_buf, out_us, Zp, hist, n);
    k2_final_collect<<<1024, 256, 0, stream>>>(e_buf, prec, out_us, hist, Zp, wgate, agate,
                                               out_ww, out_pr, cand_val, cand_idx, counter,
                                               n / 4);
    k3_select_scatter<<<1, SEL_THREADS, 0, stream>>>(cand_val, cand_idx, counter,
                                                     wgate, agate, out_ww, out_pr);
}